// Round 1
// baseline (113.093 us; speedup 1.0000x reference)
//
#include <hip/hip_runtime.h>

// TopologyAwareAttention: out = attn + lam * mean_h( MLP(topology)[h] )
// Structure exploited:
//  - mean over heads first: f(t) = sum_e relu(t*w1[e]+b1[e]) * wbar[e] + b2bar
//  - centers on 16x16 grid => dist = sqrt(dx^2+dy^2)/15, d2 = dx^2+dy^2 in [0,450]
//    => f takes <=451 distinct values per batch => LUT
// Kernels: centers argmax -> dist sum (mean) -> LUT build -> memory-bound apply.

#define NQ   900
#define NB   2
#define HW   256
#define LUT_N 451   // dx^2+dy^2 <= 15^2+15^2 = 450

__global__ __launch_bounds__(256) void centers_kernel(const float* __restrict__ ref,
                                                      int* __restrict__ centers) {
    // one wave per query; 450 blocks x 4 waves = 1800 queries
    int wave = threadIdx.x >> 6;
    int lane = threadIdx.x & 63;
    int q = blockIdx.x * 4 + wave;          // < 1800 always
    const float* p = ref + (size_t)q * HW;
    float bv = p[lane];
    int   bi = lane;
    #pragma unroll
    for (int k = 1; k < 4; ++k) {
        float v = p[lane + 64 * k];
        if (v > bv) { bv = v; bi = lane + 64 * k; }   // strictly-greater keeps first max
    }
    #pragma unroll
    for (int off = 32; off >= 1; off >>= 1) {
        float ov = __shfl_down(bv, off, 64);
        int   oi = __shfl_down(bi, off, 64);
        if (ov > bv || (ov == bv && oi < bi)) { bv = ov; bi = oi; }
    }
    if (lane == 0) centers[q] = bi;         // idx = iy*16 + ix
}

__global__ __launch_bounds__(256) void distsum_kernel(const int* __restrict__ centers,
                                                      double* __restrict__ sums) {
    int bq = blockIdx.x;                    // 0..1799  (b*900 + i)
    int b  = bq / NQ;
    int ci = centers[bq];
    int ixi = ci & 15, iyi = ci >> 4;
    float local = 0.f;
    for (int j = threadIdx.x; j < NQ; j += 256) {
        int cj = centers[b * NQ + j];
        int dx = ixi - (cj & 15);
        int dy = iyi - (cj >> 4);
        local += sqrtf((float)(dx * dx + dy * dy));
    }
    #pragma unroll
    for (int off = 32; off >= 1; off >>= 1) local += __shfl_down(local, off, 64);
    __shared__ float wsum[4];
    int lane = threadIdx.x & 63, wave = threadIdx.x >> 6;
    if (lane == 0) wsum[wave] = local;
    __syncthreads();
    if (threadIdx.x == 0) {
        float tot = wsum[0] + wsum[1] + wsum[2] + wsum[3];
        atomicAdd(&sums[b], (double)tot * (1.0 / 15.0));
    }
}

__global__ __launch_bounds__(256) void lut_kernel(const double* __restrict__ sums,
                                                  const float* __restrict__ w1,
                                                  const float* __restrict__ b1,
                                                  const float* __restrict__ w2,
                                                  const float* __restrict__ b2,
                                                  const float* __restrict__ lam_p,
                                                  float* __restrict__ lut) {
    int b = blockIdx.x;                     // 2 blocks
    __shared__ float wbar[256];
    int e = threadIdx.x;
    float s8 = 0.f;
    #pragma unroll
    for (int h = 0; h < 8; ++h) s8 += w2[e * 8 + h];
    wbar[e] = s8 * 0.125f;
    __syncthreads();
    float b2bar = 0.125f * (b2[0] + b2[1] + b2[2] + b2[3] + b2[4] + b2[5] + b2[6] + b2[7]);
    float mean  = (float)(sums[b] / ((double)NQ * (double)NQ));
    float lam   = lam_p[0];
    float inv   = 1.0f / (mean + 1e-6f);
    for (int s = threadIdx.x; s < LUT_N; s += 256) {
        float t = sqrtf((float)s) * (1.0f / 15.0f) * inv;   // topology value
        float acc = b2bar;
        for (int i = 0; i < 256; ++i) {
            float h = fmaf(t, w1[i], b1[i]);
            acc = fmaf(fmaxf(h, 0.f), wbar[i], acc);
        }
        lut[b * LUT_N + s] = lam * acc;
    }
}

__global__ __launch_bounds__(256) void apply_kernel(const float* __restrict__ attn,
                                                    const int* __restrict__ centers,
                                                    const float* __restrict__ lut,
                                                    float* __restrict__ out) {
    int b = blockIdx.y;
    __shared__ float lut_s[LUT_N];
    __shared__ int   idx_s[NQ];
    for (int k = threadIdx.x; k < LUT_N; k += 256) lut_s[k] = lut[b * LUT_N + k];
    for (int k = threadIdx.x; k < NQ;    k += 256) idx_s[k] = centers[b * NQ + k];
    __syncthreads();
    int t4 = blockIdx.x * 256 + threadIdx.x;    // one float4 per thread
    if (t4 >= NQ * NQ / 4) return;              // 202500
    int i  = t4 / 225;                          // 225 float4 per row
    int j0 = (t4 - i * 225) * 4;
    int ci = idx_s[i];
    int ixi = ci & 15, iyi = ci >> 4;
    size_t base = (size_t)b * (NQ * NQ) + (size_t)i * NQ + j0;
    float4 a = *(const float4*)(attn + base);
    float r[4] = {a.x, a.y, a.z, a.w};
    #pragma unroll
    for (int u = 0; u < 4; ++u) {
        int cj = idx_s[j0 + u];
        int dx = ixi - (cj & 15), dy = iyi - (cj >> 4);
        r[u] += lut_s[dx * dx + dy * dy];
    }
    float4 o = make_float4(r[0], r[1], r[2], r[3]);
    *(float4*)(out + base) = o;
}

extern "C" void kernel_launch(void* const* d_in, const int* in_sizes, int n_in,
                              void* d_out, int out_size, void* d_ws, size_t ws_size,
                              hipStream_t stream) {
    const float* attn = (const float*)d_in[0];   // [2,900,900]
    const float* ref  = (const float*)d_in[1];   // [2,900,16,16]
    const float* lam  = (const float*)d_in[2];   // scalar
    const float* w1   = (const float*)d_in[3];   // [256]
    const float* b1   = (const float*)d_in[4];   // [256]
    const float* w2   = (const float*)d_in[5];   // [256,8]
    const float* b2   = (const float*)d_in[6];   // [8]
    float* out = (float*)d_out;

    char* ws = (char*)d_ws;
    double* sums   = (double*)ws;                 // 2 doubles (16 B)
    int*    cent   = (int*)(ws + 16);             // 1800 ints
    float*  lut    = (float*)(ws + 16 + 1800 * 4);// 2*451 floats

    hipMemsetAsync(sums, 0, 2 * sizeof(double), stream);
    centers_kernel<<<450, 256, 0, stream>>>(ref, cent);
    distsum_kernel<<<1800, 256, 0, stream>>>(cent, sums);
    lut_kernel<<<2, 256, 0, stream>>>(sums, w1, b1, w2, b2, lam, lut);
    apply_kernel<<<dim3((NQ * NQ / 4 + 255) / 256, NB), 256, 0, stream>>>(attn, cent, lut, out);
}